// Round 2
// baseline (382.507 us; speedup 1.0000x reference)
//
#include <hip/hip_runtime.h>
#include <hip/hip_bf16.h>

// GPConv1d: out[b,o,kb,w] = sum_{i,j,c,v} G[i,j,kb] W[v,c,o,i] xpad[b,c,j,w+v] + bias[o,kb]
// == GEMM: out[ok][b,w] = kern[ok][kd] * X[kd][b,w],  M=512, N=32768, K=2560
//   kern[ok][kd] = sum_i G[i,j,kb] W[v,c,o,i],  ok=o*8+kb, kd=v*512+(c*8+j)  (v-major!)
//   X[kd][b,w]   = x[b][cj][w+v-2]  (zero-padded)  -- contiguous in w => transpose on LDS stage

#define NB_   8
#define C_    64
#define O_    64
#define BD_   8
#define L_    4096
#define PAD_  2
#define CJ_   512
#define OKch  512
#define KD_   2560

#define BM 128
#define BN 128
#define BK 32
#define BNP 40   // Bs row stride (elems): 32 + 8 pad to break write-bank conflicts

typedef __bf16 bf16x8 __attribute__((ext_vector_type(8)));
typedef float floatx4 __attribute__((ext_vector_type(4)));

__device__ __forceinline__ unsigned short f2bf(float f) {
    // round-to-nearest-even fp32 -> bf16 (inputs finite; no NaN handling needed)
    unsigned int u = __float_as_uint(f);
    u += 0x7FFFu + ((u >> 16) & 1u);
    return (unsigned short)(u >> 16);
}

__device__ __forceinline__ void glds16(const unsigned short* g, unsigned short* l) {
    // async global->LDS, 16B per lane; LDS dest = wave-uniform base + lane*16
    // C-style casts: allowed to change address space + drop qualifiers
    __builtin_amdgcn_global_load_lds(
        (const __attribute__((address_space(1))) unsigned int*)(g),
        (__attribute__((address_space(3))) unsigned int*)(l),
        16, 0, 0);
}

// ---- kernel 1: kern_bf16[ok][v*512+cj] = sum_i G[i*64+j*8+kb] * W[((v*64+c)*64+o)*8+i]
__global__ __launch_bounds__(256) void build_kern(
    const float* __restrict__ W, const float* __restrict__ G,
    unsigned short* __restrict__ kern)
{
    const int ok = blockIdx.y;                    // 0..511
    const int kd = blockIdx.x * 256 + threadIdx.x; // 0..2559
    const int v  = kd >> 9;
    const int cj = kd & 511;
    const int c  = cj >> 3;
    const int j  = cj & 7;
    const int o  = ok >> 3;
    const int kb = ok & 7;
    const float* Wp = W + (((v * C_ + c) * O_ + o) << 3);  // 8 i-contiguous floats
    const float4 w0 = *(const float4*)Wp;
    const float4 w1 = *(const float4*)(Wp + 4);
    const int gb = j * 8 + kb;                    // G[i][j][kb], i stride 64
    float s = G[gb]       * w0.x + G[gb + 64]  * w0.y
            + G[gb + 128] * w0.z + G[gb + 192] * w0.w
            + G[gb + 256] * w1.x + G[gb + 320] * w1.y
            + G[gb + 384] * w1.z + G[gb + 448] * w1.w;
    kern[ok * KD_ + kd] = f2bf(s);
}

// ---- kernel 2: implicit-im2col bf16 MFMA GEMM, 128x128 C-tile, BK=32, 4 waves
__global__ __launch_bounds__(256) void gpconv_mfma(
    const float* __restrict__ x, const unsigned short* __restrict__ kern,
    const float* __restrict__ bias, float* __restrict__ out)
{
    __shared__ unsigned short As[BM * BK];   // [m][kk], 64B rows (glds-contiguous, no pad)
    __shared__ unsigned short Bs[BN * BNP];  // [n][kk], 80B rows (padded)

    const int tid  = threadIdx.x;
    const int lane = tid & 63;
    const int wave = tid >> 6;
    const int lrow = lane & 15;
    const int quad = lane >> 4;
    const int wm = (wave >> 1) << 6;   // wave row offset (2x2 wave grid, 64x64 each)
    const int wn = (wave & 1) << 6;

    const int mBase = blockIdx.y * BM;            // 0,128,256,384
    const int b     = blockIdx.x >> 5;            // 32 w-tiles per batch
    const int w0    = (blockIdx.x & 31) * BN;
    const float* xb = x + (size_t)b * (size_t)(CJ_ * L_);

    const int n0  = tid & 127;   // B-stage: this thread's w-offset
    const int kg0 = tid >> 7;    // and k-group (8 kd rows per group)

    floatx4 acc[4][4];
    {
        const floatx4 z = {0.f, 0.f, 0.f, 0.f};
        #pragma unroll
        for (int i2 = 0; i2 < 4; i2++)
            #pragma unroll
            for (int j2 = 0; j2 < 4; j2++) acc[i2][j2] = z;
    }

    for (int kd0 = 0; kd0 < KD_; kd0 += BK) {
        // ---- stage A: 2 x 16B async per thread; chunk i -> row i/4, kk (i%4)*8
        #pragma unroll
        for (int ch = 0; ch < 2; ch++) {
            const int i = tid + (ch << 8);
            const unsigned short* g =
                kern + (size_t)(mBase + (i >> 2)) * KD_ + (size_t)(kd0 + ((i & 3) << 3));
            glds16(g, &As[i << 3]);
        }
        // ---- stage B: transpose-in-register. 2 tasks: 8 coalesced dword loads -> pack -> b128 write
        #pragma unroll
        for (int t2 = 0; t2 < 2; t2++) {
            const int kg  = kg0 + (t2 << 1);      // 0..3
            const int kdb = kd0 + (kg << 3);
            unsigned int pk[4];
            #pragma unroll
            for (int r = 0; r < 8; r++) {
                const int kd = kdb + r;
                const int v  = kd >> 9;           // v-major kd: shifts, no div
                const int cj = kd & 511;
                const int ws = w0 + n0 - PAD_ + v;
                float val = 0.f;
                if ((unsigned)ws < (unsigned)L_) val = xb[((size_t)cj << 12) + (size_t)ws];
                const unsigned int h = f2bf(val);
                if (r & 1) pk[r >> 1] |= h << 16;
                else       pk[r >> 1]  = h;
            }
            uint4 u; u.x = pk[0]; u.y = pk[1]; u.z = pk[2]; u.w = pk[3];
            *reinterpret_cast<uint4*>(&Bs[n0 * BNP + (kg << 3)]) = u;
        }
        __syncthreads();

        // ---- compute: 4 a-frags + 4 b-frags (ds_read_b128), 16 MFMA
        bf16x8 af[4], bfr[4];
        #pragma unroll
        for (int mt = 0; mt < 4; mt++)
            af[mt] = *reinterpret_cast<const bf16x8*>(
                &As[((wm + (mt << 4) + lrow) << 5) + (quad << 3)]);
        #pragma unroll
        for (int nt = 0; nt < 4; nt++)
            bfr[nt] = *reinterpret_cast<const bf16x8*>(
                &Bs[(wn + (nt << 4) + lrow) * BNP + (quad << 3)]);
        #pragma unroll
        for (int mt = 0; mt < 4; mt++)
            #pragma unroll
            for (int nt = 0; nt < 4; nt++)
                acc[mt][nt] = __builtin_amdgcn_mfma_f32_16x16x32_bf16(
                    af[mt], bfr[nt], acc[mt][nt], 0, 0, 0);
        __syncthreads();
    }

    // ---- epilogue: C/D layout col=lane&15 (n), row=quad*4+e (m); add bias, store fp32
    #pragma unroll
    for (int mt = 0; mt < 4; mt++) {
        #pragma unroll
        for (int e = 0; e < 4; e++) {
            const int okc = mBase + wm + (mt << 4) + (quad << 2) + e;
            const float bv = bias[okc];
            float* orow = out + ((size_t)b * OKch + (size_t)okc) * L_ + w0;
            #pragma unroll
            for (int nt = 0; nt < 4; nt++) {
                const int n = wn + (nt << 4) + lrow;
                orow[n] = acc[mt][nt][e] + bv;
            }
        }
    }
}

extern "C" void kernel_launch(void* const* d_in, const int* in_sizes, int n_in,
                              void* d_out, int out_size, void* d_ws, size_t ws_size,
                              hipStream_t stream) {
    const float* x    = (const float*)d_in[0];  // (8,64,8,4096)
    const float* W    = (const float*)d_in[1];  // (5,64,64,8)
    const float* bias = (const float*)d_in[2];  // (1,64,8,1) -> [512]
    const float* G    = (const float*)d_in[3];  // (8,8,8)
    unsigned short* kern = (unsigned short*)d_ws;  // 512*2560 bf16 = 2.62 MB
    float* out = (float*)d_out;                 // (8,64,8,4096) fp32

    build_kern<<<dim3(KD_ / 256, OKch), 256, 0, stream>>>(W, G, kern);
    gpconv_mfma<<<dim3(256, 4), 256, 0, stream>>>(x, kern, bias, out);
}

// Round 3
// 233.422 us; speedup vs baseline: 1.6387x; 1.6387x over previous
//
#include <hip/hip_runtime.h>
#include <hip/hip_bf16.h>

// GPConv1d: out[b,o,kb,w] = sum_{i,j,c,v} G[i,j,kb] W[v,c,o,i] xpad[b,c,j,w+v] + bias[o,kb]
// GEMM view: out[ok][b,w] = sum_kd kern[ok][kd] X[kd][b,w], M=512, N=32768, K=2560
//   kd = (v, cj): X[(v,cj)][b,w] = x[b][cj][w+v-2] (zero-padded)
// K-loop restructured: outer over cj-blocks (64 cj), inner over v (5 shifts).
// The x window Bs[nn][kk] (nn = w0-2 .. w0+129, kk = cj) is staged ONCE per
// cj-block and serves all 5 v's (b-frag for shift v = row n+v): 5x less x traffic.
// kern is pre-tiled (build_kern) into glds-ready tiles with pad baked in:
// tile(y,cjb,v) = [m=0..127][kk=0..63 + 8 pad], stride 72 elems (144B) ->
// conflict-free (2-way) fragment reads for both A and B.

#define C_    64
#define L_    4096
#define PAD_  2
#define CJ_   512
#define OKch  512
#define KD_   2560

#define BM    128
#define BN    128
#define BKCJ  64        // cj per block-tile
#define NCJB  8         // 512/64
#define NV    5
#define ASTR  72        // row stride (elems) for As and Bs: 64 + 8 pad
#define TILE_ELEMS (128 * ASTR)   // 9216 elems = 18432 B per kern tile
#define NCHUNK (TILE_ELEMS * 2 / 16)  // 1152 x 16B glds chunks per tile
#define WIN   132       // Bs rows: w0-2 .. w0+129

typedef __bf16 bf16x8 __attribute__((ext_vector_type(8)));
typedef float floatx4 __attribute__((ext_vector_type(4)));

__device__ __forceinline__ unsigned short f2bf(float f) {
    unsigned int u = __float_as_uint(f);
    u += 0x7FFFu + ((u >> 16) & 1u);
    return (unsigned short)(u >> 16);
}

__device__ __forceinline__ void glds16(const unsigned short* g, unsigned short* l) {
    __builtin_amdgcn_global_load_lds(
        (const __attribute__((address_space(1))) unsigned int*)(g),
        (__attribute__((address_space(3))) unsigned int*)(l),
        16, 0, 0);
}

// ---- kernel 1: build kern, tiled+padded for direct glds staging.
// kern value for (ok, kd=(v,cj)) = sum_i G[i,j,kb] W[v,c,o,i], cj=c*8+j, ok=o*8+kb
// stored at tile ((y*8+cjb)*5+v), elem m*72 + kk,  y=ok>>7, m=ok&127, cjb=cj>>6, kk=cj&63
__global__ __launch_bounds__(256) void build_kern(
    const float* __restrict__ W, const float* __restrict__ G,
    unsigned short* __restrict__ kernT)
{
    const int ok = blockIdx.y;                     // 0..511
    const int kd = blockIdx.x * 256 + threadIdx.x; // 0..2559
    const int v  = kd >> 9;
    const int cj = kd & 511;
    const int c  = cj >> 3;
    const int j  = cj & 7;
    const int o  = ok >> 3;
    const int kb = ok & 7;
    const float* Wp = W + (((v * C_ + c) * 64 + o) << 3);  // 8 i-contiguous floats
    const float4 w0 = *(const float4*)Wp;
    const float4 w1 = *(const float4*)(Wp + 4);
    const int gb = j * 8 + kb;                     // G[i][j][kb], i stride 64
    float s = G[gb]       * w0.x + G[gb + 64]  * w0.y
            + G[gb + 128] * w0.z + G[gb + 192] * w0.w
            + G[gb + 256] * w1.x + G[gb + 320] * w1.y
            + G[gb + 384] * w1.z + G[gb + 448] * w1.w;
    const int y   = ok >> 7;
    const int m   = ok & 127;
    const int cjb = cj >> 6;
    const int kk  = cj & 63;
    kernT[(size_t)(((y * NCJB + cjb) * NV + v)) * TILE_ELEMS + m * ASTR + kk] = f2bf(s);
}

// ---- kernel 2: MFMA GEMM, 128x128 C-tile, K-loop = (cjb outer, v inner)
__global__ __launch_bounds__(256) void gpconv_mfma(
    const float* __restrict__ x, const unsigned short* __restrict__ kernT,
    const float* __restrict__ bias, float* __restrict__ out)
{
    __shared__ unsigned short As[128 * ASTR];  // kern tile (one v), 18432 B
    __shared__ unsigned short Bs[WIN * ASTR];  // x window, 19008 B

    const int tid  = threadIdx.x;
    const int lane = tid & 63;
    const int wave = tid >> 6;
    const int lrow = lane & 15;
    const int quad = lane >> 4;
    const int wm = (wave >> 1) << 6;   // 2x2 wave grid, 64x64 each
    const int wn = (wave & 1) << 6;

    // XCD-aware remap: 4 y-blocks sharing an x-window land on the same XCD
    // (linear ids differing by 8 -> same id mod 8 -> same XCD round-robin slot)
    const int bid = blockIdx.x;              // 0..1023
    const int y   = (bid >> 3) & 3;
    const int xw  = ((bid >> 5) << 3) + (bid & 7);  // 0..255
    const int b   = xw >> 5;
    const int w0  = (xw & 31) * BN;
    const int mBase = y * BM;
    const float* xb = x + (size_t)b * (size_t)(CJ_ * L_);
    const unsigned short* ky = kernT + (size_t)(y * NCJB) * NV * TILE_ELEMS;

    floatx4 acc[4][4];
    {
        const floatx4 z = {0.f, 0.f, 0.f, 0.f};
        #pragma unroll
        for (int i2 = 0; i2 < 4; i2++)
            #pragma unroll
            for (int j2 = 0; j2 < 4; j2++) acc[i2][j2] = z;
    }

    for (int cjb = 0; cjb < NCJB; cjb++) {
        const int cj0 = cjb * BKCJ;
        const unsigned short* tile = ky + (size_t)(cjb * NV) * TILE_ELEMS;

        __syncthreads();   // previous iter's As/Bs reads complete

        // ---- stage B window: transpose x[cj0..+64][w0-2 .. w0+129] -> Bs[nn][kk]
        #pragma unroll
        for (int u = 0; u < 5; u++) {
            const int t = tid + u * 256;
            if (t < WIN * 8) {
                const int kgrp = t / WIN;          // 0..7
                const int nn   = t - kgrp * WIN;   // 0..131
                const int ws   = w0 - PAD_ + nn;
                const int cjw  = cj0 + (kgrp << 3);
                unsigned int pk[4];
                #pragma unroll
                for (int r = 0; r < 8; r++) {
                    float val = 0.f;
                    if ((unsigned)ws < (unsigned)L_)
                        val = xb[((size_t)(cjw + r) << 12) + (size_t)ws];
                    const unsigned int h = f2bf(val);
                    if (r & 1) pk[r >> 1] |= h << 16;
                    else       pk[r >> 1]  = h;
                }
                uint4 uu; uu.x = pk[0]; uu.y = pk[1]; uu.z = pk[2]; uu.w = pk[3];
                *reinterpret_cast<uint4*>(&Bs[nn * ASTR + (kgrp << 3)]) = uu;
            }
        }
        // ---- stage A tile for v=0 (async, straight into padded layout)
        #pragma unroll
        for (int u = 0; u < 5; u++) {
            const int i = tid + u * 256;
            if (i < NCHUNK) glds16(tile + (i << 3), &As[i << 3]);
        }
        __syncthreads();   // Bs written, glds drained (barrier implies vmcnt(0))

        #pragma unroll
        for (int v = 0; v < NV; v++) {
            if (v > 0) {
                __syncthreads();   // frag reads of v-1 done
                const unsigned short* tv = tile + (size_t)v * TILE_ELEMS;
                #pragma unroll
                for (int u = 0; u < 5; u++) {
                    const int i = tid + u * 256;
                    if (i < NCHUNK) glds16(tv + (i << 3), &As[i << 3]);
                }
                __syncthreads();   // As(v) visible
            }
            // ---- compute: per 32-wide k-chunk, 8 frag reads + 16 MFMA
            #pragma unroll
            for (int kk2 = 0; kk2 < 2; kk2++) {
                bf16x8 af[4], bfr[4];
                #pragma unroll
                for (int mt = 0; mt < 4; mt++)
                    af[mt] = *reinterpret_cast<const bf16x8*>(
                        &As[(wm + (mt << 4) + lrow) * ASTR + (kk2 << 5) + (quad << 3)]);
                #pragma unroll
                for (int nt = 0; nt < 4; nt++)
                    bfr[nt] = *reinterpret_cast<const bf16x8*>(
                        &Bs[(wn + (nt << 4) + lrow + v) * ASTR + (kk2 << 5) + (quad << 3)]);
                #pragma unroll
                for (int mt = 0; mt < 4; mt++)
                    #pragma unroll
                    for (int nt = 0; nt < 4; nt++)
                        acc[mt][nt] = __builtin_amdgcn_mfma_f32_16x16x32_bf16(
                            af[mt], bfr[nt], acc[mt][nt], 0, 0, 0);
            }
        }
    }

    // ---- epilogue: C/D layout col(n)=lane&15, row(m)=quad*4+e
    #pragma unroll
    for (int mt = 0; mt < 4; mt++) {
        #pragma unroll
        for (int e = 0; e < 4; e++) {
            const int okc = mBase + wm + (mt << 4) + (quad << 2) + e;
            const float bv = bias[okc];
            float* orow = out + ((size_t)b * OKch + (size_t)okc) * L_ + w0;
            #pragma unroll
            for (int nt = 0; nt < 4; nt++) {
                const int n = wn + (nt << 4) + lrow;
                orow[n] = acc[mt][nt][e] + bv;
            }
        }
    }
}

extern "C" void kernel_launch(void* const* d_in, const int* in_sizes, int n_in,
                              void* d_out, int out_size, void* d_ws, size_t ws_size,
                              hipStream_t stream) {
    const float* x    = (const float*)d_in[0];  // (8,64,8,4096)
    const float* W    = (const float*)d_in[1];  // (5,64,64,8)
    const float* bias = (const float*)d_in[2];  // (1,64,8,1) -> [512]
    const float* G    = (const float*)d_in[3];  // (8,8,8)
    unsigned short* kernT = (unsigned short*)d_ws;  // 160 tiles x 18432 B = 2.95 MB
    float* out = (float*)d_out;

    build_kern<<<dim3(KD_ / 256, OKch), 256, 0, stream>>>(W, G, kernT);
    gpconv_mfma<<<dim3(1024), 256, 0, stream>>>(x, kernT, bias, out);
}